// Round 1
// baseline (892.330 us; speedup 1.0000x reference)
//
#include <hip/hip_runtime.h>
#include <cstddef>
#include <cstdint>

#define B_    2
#define S_    2048
#define DIN_  1024
#define H_    16
#define DK_   1024
#define DV_   1024
#define DH_   64
#define DOUT_ 1024
#define M_    (B_ * S_)

typedef __attribute__((ext_vector_type(8))) short  short8;
typedef __attribute__((ext_vector_type(4))) float  float4v;

__device__ __forceinline__ float bf16s_to_f(short s) {
  union { unsigned int u; float f; } cv;
  cv.u = ((unsigned int)(unsigned short)s) << 16;
  return cv.f;
}
__device__ __forceinline__ short f_to_bf16s(float f) {
  union { float f; unsigned int u; } cv;
  cv.f = f;
  unsigned int u = cv.u + 0x7FFFu + ((cv.u >> 16) & 1u);
  return (short)(u >> 16);
}

// ---------------- cast f32 -> bf16 (4 elems/thread) ----------------
__global__ __launch_bounds__(256) void cast_kernel(const float* __restrict__ in,
                                                   short* __restrict__ out, int n4) {
  int i = blockIdx.x * 256 + threadIdx.x;
  if (i >= n4) return;
  float4 v = ((const float4*)in)[i];
  union { ushort4 u; short s[4]; } o;
  o.s[0] = f_to_bf16s(v.x); o.s[1] = f_to_bf16s(v.y);
  o.s[2] = f_to_bf16s(v.z); o.s[3] = f_to_bf16s(v.w);
  ((ushort4*)out)[i] = o.u;
}

// ---------------- content bias: CBs[b,h,s] = scale*log2e*dot(x[b,s,:],Wcb[h,:]) ----
__global__ __launch_bounds__(256) void cb_kernel(const float* __restrict__ x,
                                                 const float* __restrict__ Wcb,
                                                 float* __restrict__ CBs) {
  __shared__ float xs[DIN_];
  const int row = blockIdx.x;  // b*S + s
  const int tid = threadIdx.x;
  #pragma unroll
  for (int it = 0; it < 4; ++it)
    xs[tid + it * 256] = x[(size_t)row * DIN_ + tid + it * 256];
  __syncthreads();
  const int lane = tid & 63, w = tid >> 6;
  const float SC = 0.125f * 1.44269504088896f;
  #pragma unroll
  for (int hh = 0; hh < 4; ++hh) {
    const int hidx = w * 4 + hh;
    float p = 0.f;
    for (int c = lane; c < DIN_; c += 64)
      p += xs[c] * Wcb[(size_t)hidx * DIN_ + c];
    #pragma unroll
    for (int mk = 1; mk < 64; mk <<= 1) p += __shfl_xor(p, mk);
    if (lane == 0) {
      const int bb = row / S_, ss = row % S_;
      CBs[((size_t)bb * H_ + hidx) * S_ + ss] = p * SC;
    }
  }
}

// ---------------- bf16 NT GEMM: C[M,1024] = A[M,1024] * Bw[1024,1024]^T ----------
// mode 0: outb = bf16(acc); mode 1: outb = bf16(acc + bias); mode 2: outf = acc + bias + resid
__global__ __launch_bounds__(256, 2) void gemm_nt(
    const short* __restrict__ A, const short* __restrict__ Bw,
    const float* __restrict__ bias, const float* __restrict__ resid,
    short* __restrict__ outb, float* __restrict__ outf, int mode) {
  const int KD = 1024, ND = 1024;
  __shared__ short As[64][72];   // +8 pad: dword stride 36 -> banks spread
  __shared__ short Bs[64][72];
  const int tid  = threadIdx.x;
  const int lane = tid & 63;
  const int w    = tid >> 6;
  const int quad = lane >> 4;
  const int l16  = lane & 15;
  const int m0   = blockIdx.y * 64;
  const int n0   = blockIdx.x * 64;
  const int wm   = (w >> 1) * 32;
  const int wn   = (w & 1) * 32;

  const float4v zero = {0.f, 0.f, 0.f, 0.f};
  float4v acc[2][2];
  acc[0][0] = zero; acc[0][1] = zero; acc[1][0] = zero; acc[1][1] = zero;

  for (int k0 = 0; k0 < KD; k0 += 64) {
    __syncthreads();
    #pragma unroll
    for (int it = 0; it < 2; ++it) {
      int idx = tid + it * 256;
      int row = idx >> 3, seg = idx & 7;
      *(short8*)&As[row][seg * 8] =
          *(const short8*)(A + (size_t)(m0 + row) * KD + k0 + seg * 8);
      *(short8*)&Bs[row][seg * 8] =
          *(const short8*)(Bw + (size_t)(n0 + row) * KD + k0 + seg * 8);
    }
    __syncthreads();
    #pragma unroll
    for (int ks = 0; ks < 2; ++ks) {
      short8 af0 = *(short8*)&As[wm + l16][ks * 32 + quad * 8];
      short8 af1 = *(short8*)&As[wm + 16 + l16][ks * 32 + quad * 8];
      short8 bg0 = *(short8*)&Bs[wn + l16][ks * 32 + quad * 8];
      short8 bg1 = *(short8*)&Bs[wn + 16 + l16][ks * 32 + quad * 8];
      acc[0][0] = __builtin_amdgcn_mfma_f32_16x16x32_bf16(af0, bg0, acc[0][0], 0, 0, 0);
      acc[0][1] = __builtin_amdgcn_mfma_f32_16x16x32_bf16(af0, bg1, acc[0][1], 0, 0, 0);
      acc[1][0] = __builtin_amdgcn_mfma_f32_16x16x32_bf16(af1, bg0, acc[1][0], 0, 0, 0);
      acc[1][1] = __builtin_amdgcn_mfma_f32_16x16x32_bf16(af1, bg1, acc[1][1], 0, 0, 0);
    }
  }

  #pragma unroll
  for (int mt = 0; mt < 2; ++mt)
    #pragma unroll
    for (int nt = 0; nt < 2; ++nt)
      #pragma unroll
      for (int r = 0; r < 4; ++r) {
        int row = m0 + wm + mt * 16 + quad * 4 + r;  // verified C/D layout
        int col = n0 + wn + nt * 16 + l16;
        float v = acc[mt][nt][r];
        if (mode >= 1) v += bias[col];
        if (mode == 2)
          outf[(size_t)row * ND + col] = v + resid[(size_t)row * ND + col];
        else
          outb[(size_t)row * ND + col] = f_to_bf16s(v);
      }
}

// ---------------- fused collaborative attention (flash-style) ----------------
// grid (S/64, H, B); 4 waves, each owns 16 query rows; Qm (mix*scale*log2e folded,
// bf16) lives entirely in registers (32 frags = 128 VGPRs).
__global__ __launch_bounds__(256, 2) void attn_kernel(
    const short* __restrict__ Qb, const short* __restrict__ Kb,
    const short* __restrict__ Vb, const float* __restrict__ mixing,
    const float* __restrict__ CBs, short* __restrict__ ctxb) {
  __shared__ short Ks[32][264];     // 32 keys x 256 k-chunk (+8 pad)
  __shared__ short Vt[64][40];      // V transposed: [dv][j] (+8 pad)
  __shared__ short Pa[4][16][40];   // per-wave P in A-layout [m][j]

  const int tid  = threadIdx.x;
  const int lane = tid & 63;
  const int w    = tid >> 6;
  const int quad = lane >> 4;
  const int l16  = lane & 15;
  const int i0   = blockIdx.x * 64;
  const int h    = blockIdx.y;
  const int b    = blockIdx.z;

  // ---- Qm fragments -> registers ----
  short8 qm[32];
  {
    const int qrow = i0 + w * 16 + l16;
    const short* qptr = Qb + ((size_t)b * S_ + qrow) * DK_;
    const float* mix  = mixing + (size_t)h * DK_;
    const float QS = 0.125f * 1.44269504088896f;  // 1/sqrt(64) * log2(e)
    #pragma unroll
    for (int kt = 0; kt < 32; ++kt) {
      const int kb = kt * 32 + quad * 8;
      short8 qv = *(const short8*)(qptr + kb);
      short8 o;
      #pragma unroll
      for (int e = 0; e < 8; ++e)
        o[e] = f_to_bf16s(bf16s_to_f(qv[e]) * (mix[kb + e] * QS));
      qm[kt] = o;
    }
  }

  const float4v zero = {0.f, 0.f, 0.f, 0.f};
  float4v accO[4];
  #pragma unroll
  for (int t = 0; t < 4; ++t) accO[t] = zero;
  float m_run[4] = {-1e30f, -1e30f, -1e30f, -1e30f};
  float l_run[4] = {0.f, 0.f, 0.f, 0.f};

  const short* kbase = Kb + (size_t)b * S_ * DK_;
  const short* vbase = Vb + (size_t)b * S_ * DV_ + h * DH_;
  const float* cbp   = CBs + ((size_t)b * H_ + h) * S_;

  for (int j0 = 0; j0 < S_; j0 += 32) {
    __syncthreads();  // prev iter's Vt/Ks reads done
    {   // stage V transposed: 32 j x 64 dv
      const int j = tid >> 3, seg = tid & 7;
      short8 vv = *(const short8*)(vbase + (size_t)(j0 + j) * DV_ + seg * 8);
      #pragma unroll
      for (int e = 0; e < 8; ++e) Vt[seg * 8 + e][j] = vv[e];
    }
    float4v accS0 = zero, accS1 = zero;
    #pragma unroll
    for (int kc = 0; kc < 4; ++kc) {
      __syncthreads();
      #pragma unroll
      for (int it = 0; it < 4; ++it) {   // stage K chunk: 32 rows x 256 k
        const int idx = tid + it * 256;
        const int row = idx >> 5, seg = idx & 31;
        *(short8*)&Ks[row][seg * 8] =
            *(const short8*)(kbase + (size_t)(j0 + row) * DK_ + kc * 256 + seg * 8);
      }
      __syncthreads();
      #pragma unroll
      for (int ks = 0; ks < 8; ++ks) {
        short8 b0 = *(short8*)&Ks[l16][ks * 32 + quad * 8];
        short8 b1 = *(short8*)&Ks[16 + l16][ks * 32 + quad * 8];
        accS0 = __builtin_amdgcn_mfma_f32_16x16x32_bf16(qm[kc * 8 + ks], b0, accS0, 0, 0, 0);
        accS1 = __builtin_amdgcn_mfma_f32_16x16x32_bf16(qm[kc * 8 + ks], b1, accS1, 0, 0, 0);
      }
    }
    // ---- online softmax (rows = quad*4+r), scores already in log2 units ----
    const float cb0 = cbp[j0 + l16];
    const float cb1 = cbp[j0 + 16 + l16];
    float alpha[4];
    #pragma unroll
    for (int r = 0; r < 4; ++r) {
      float s0 = accS0[r] + cb0;
      float s1 = accS1[r] + cb1;
      float mx = fmaxf(s0, s1);
      mx = fmaxf(mx, __shfl_xor(mx, 1));
      mx = fmaxf(mx, __shfl_xor(mx, 2));
      mx = fmaxf(mx, __shfl_xor(mx, 4));
      mx = fmaxf(mx, __shfl_xor(mx, 8));
      const float mnew = fmaxf(m_run[r], mx);
      alpha[r] = exp2f(m_run[r] - mnew);
      const float p0 = exp2f(s0 - mnew);
      const float p1 = exp2f(s1 - mnew);
      float sum = p0 + p1;
      sum += __shfl_xor(sum, 1);
      sum += __shfl_xor(sum, 2);
      sum += __shfl_xor(sum, 4);
      sum += __shfl_xor(sum, 8);
      l_run[r] = l_run[r] * alpha[r] + sum;
      m_run[r] = mnew;
      Pa[w][quad * 4 + r][l16]      = f_to_bf16s(p0);
      Pa[w][quad * 4 + r][16 + l16] = f_to_bf16s(p1);
    }
    float4v av;
    av[0] = alpha[0]; av[1] = alpha[1]; av[2] = alpha[2]; av[3] = alpha[3];
    #pragma unroll
    for (int t = 0; t < 4; ++t) accO[t] = accO[t] * av;
    __syncthreads();  // Pa visible (and lgkm drained) before A-layout reads
    // ---- PV: O[16x64] += P[16x32] @ V[32x64] ----
    short8 pf = *(short8*)&Pa[w][l16][quad * 8];
    #pragma unroll
    for (int nt = 0; nt < 4; ++nt) {
      short8 vf = *(short8*)&Vt[nt * 16 + l16][quad * 8];
      accO[nt] = __builtin_amdgcn_mfma_f32_16x16x32_bf16(pf, vf, accO[nt], 0, 0, 0);
    }
  }

  const int orow = i0 + w * 16 + quad * 4;
  #pragma unroll
  for (int r = 0; r < 4; ++r) {
    const float rl = 1.0f / l_run[r];
    #pragma unroll
    for (int nt = 0; nt < 4; ++nt)
      ctxb[((size_t)b * S_ + orow + r) * DV_ + h * DH_ + nt * 16 + l16] =
          f_to_bf16s(accO[nt][r] * rl);
  }
}

// ---------------- LayerNorm in-place on d_out ----------------
__global__ __launch_bounds__(256) void ln_kernel(float* __restrict__ out,
                                                 const float* __restrict__ gamma,
                                                 const float* __restrict__ beta) {
  __shared__ float red[8];
  const int row = blockIdx.x;
  const int tid = threadIdx.x;
  float* p = out + (size_t)row * DOUT_;
  float4 v = ((const float4*)p)[tid];
  float s = v.x + v.y + v.z + v.w;
  #pragma unroll
  for (int mk = 1; mk < 64; mk <<= 1) s += __shfl_xor(s, mk);
  if ((tid & 63) == 0) red[tid >> 6] = s;
  __syncthreads();
  const float mean = (red[0] + red[1] + red[2] + red[3]) * (1.0f / 1024.0f);
  const float d0 = v.x - mean, d1 = v.y - mean, d2 = v.z - mean, d3 = v.w - mean;
  float sq = d0 * d0 + d1 * d1 + d2 * d2 + d3 * d3;
  #pragma unroll
  for (int mk = 1; mk < 64; mk <<= 1) sq += __shfl_xor(sq, mk);
  if ((tid & 63) == 0) red[4 + (tid >> 6)] = sq;
  __syncthreads();
  const float var = (red[4] + red[5] + red[6] + red[7]) * (1.0f / 1024.0f);
  const float rstd = rsqrtf(var + 1e-5f);
  float4 g = ((const float4*)gamma)[tid];
  float4 bt = ((const float4*)beta)[tid];
  float4 o;
  o.x = d0 * rstd * g.x + bt.x;
  o.y = d1 * rstd * g.y + bt.y;
  o.z = d2 * rstd * g.z + bt.z;
  o.w = d3 * rstd * g.w + bt.w;
  ((float4*)p)[tid] = o;
}

extern "C" void kernel_launch(void* const* d_in, const int* in_sizes, int n_in,
                              void* d_out, int out_size, void* d_ws, size_t ws_size,
                              hipStream_t stream) {
  (void)in_sizes; (void)n_in; (void)out_size; (void)ws_size;
  const float* x      = (const float*)d_in[0];
  const float* Wq     = (const float*)d_in[1];
  const float* Wk     = (const float*)d_in[2];
  const float* Wcb    = (const float*)d_in[3];
  const float* Wv     = (const float*)d_in[4];
  const float* bv     = (const float*)d_in[5];
  const float* mixing = (const float*)d_in[6];
  const float* Wd     = (const float*)d_in[7];
  const float* bd     = (const float*)d_in[8];
  const float* gamma  = (const float*)d_in[9];
  const float* beta   = (const float*)d_in[10];
  float* out = (float*)d_out;

  short* p = (short*)d_ws;
  short* xb   = p; p += (size_t)M_ * DIN_;
  short* Qb   = p; p += (size_t)M_ * DK_;
  short* Kb   = p; p += (size_t)M_ * DK_;
  short* Vb   = p; p += (size_t)M_ * DV_;
  short* ctxb = p; p += (size_t)M_ * DV_;
  short* Wqb  = p; p += (size_t)DK_ * DIN_;
  short* Wkb  = p; p += (size_t)DK_ * DIN_;
  short* Wvb  = p; p += (size_t)DV_ * DIN_;
  short* Wdb  = p; p += (size_t)DOUT_ * DV_;
  float* CBs  = (float*)p;   // B*H*S floats

  cast_kernel<<<dim3(M_ * DIN_ / 1024), 256, 0, stream>>>(x, xb, M_ * DIN_ / 4);
  cast_kernel<<<dim3(DK_ * DIN_ / 1024), 256, 0, stream>>>(Wq, Wqb, DK_ * DIN_ / 4);
  cast_kernel<<<dim3(DK_ * DIN_ / 1024), 256, 0, stream>>>(Wk, Wkb, DK_ * DIN_ / 4);
  cast_kernel<<<dim3(DV_ * DIN_ / 1024), 256, 0, stream>>>(Wv, Wvb, DV_ * DIN_ / 4);
  cast_kernel<<<dim3(DOUT_ * DV_ / 1024), 256, 0, stream>>>(Wd, Wdb, DOUT_ * DV_ / 4);
  cb_kernel<<<dim3(M_), 256, 0, stream>>>(x, Wcb, CBs);

  dim3 gg(DOUT_ / 64, M_ / 64);
  gemm_nt<<<gg, 256, 0, stream>>>(xb, Wqb, nullptr, nullptr, Qb, nullptr, 0);
  gemm_nt<<<gg, 256, 0, stream>>>(xb, Wkb, nullptr, nullptr, Kb, nullptr, 0);
  gemm_nt<<<gg, 256, 0, stream>>>(xb, Wvb, bv, nullptr, Vb, nullptr, 1);

  attn_kernel<<<dim3(S_ / 64, H_, B_), 256, 0, stream>>>(Qb, Kb, Vb, mixing, CBs, ctxb);

  gemm_nt<<<gg, 256, 0, stream>>>(ctxb, Wdb, bd, x, nullptr, out, 2);
  ln_kernel<<<dim3(M_), 256, 0, stream>>>(out, gamma, beta);
}

// Round 2
// 781.037 us; speedup vs baseline: 1.1425x; 1.1425x over previous
//
#include <hip/hip_runtime.h>
#include <cstddef>
#include <cstdint>

#define B_    2
#define S_    2048
#define DIN_  1024
#define H_    16
#define DK_   1024
#define DV_   1024
#define DH_   64
#define DOUT_ 1024
#define M_    (B_ * S_)

typedef __attribute__((ext_vector_type(8)))  short short8;
typedef __attribute__((ext_vector_type(4)))  float float4v;
typedef __attribute__((ext_vector_type(16))) float float16v;

__device__ __forceinline__ float bf16s_to_f(short s) {
  union { unsigned int u; float f; } cv;
  cv.u = ((unsigned int)(unsigned short)s) << 16;
  return cv.f;
}
__device__ __forceinline__ short f_to_bf16s(float f) {
  union { float f; unsigned int u; } cv;
  cv.f = f;
  unsigned int u = cv.u + 0x7FFFu + ((cv.u >> 16) & 1u);
  return (short)(u >> 16);
}
// (bf16(hi)<<16) | bf16(lo), truncating — 1 v_perm_b32
__device__ __forceinline__ unsigned pack2bf(float hi, float lo) {
  union { float f; unsigned u; } a, b;
  a.f = hi; b.f = lo;
  return __builtin_amdgcn_perm(a.u, b.u, 0x07060302u);
}

// ---------------- cast f32 -> bf16 (4 elems/thread) ----------------
__global__ __launch_bounds__(256) void cast_kernel(const float* __restrict__ in,
                                                   short* __restrict__ out, int n4) {
  int i = blockIdx.x * 256 + threadIdx.x;
  if (i >= n4) return;
  float4 v = ((const float4*)in)[i];
  union { ushort4 u; short s[4]; } o;
  o.s[0] = f_to_bf16s(v.x); o.s[1] = f_to_bf16s(v.y);
  o.s[2] = f_to_bf16s(v.z); o.s[3] = f_to_bf16s(v.w);
  ((ushort4*)out)[i] = o.u;
}

// ---------------- content bias: CBs[b,h,s] = SC*dot(x[b,s,:],Wcb[h,:]) ----
__global__ __launch_bounds__(256) void cb_kernel(const float* __restrict__ x,
                                                 const float* __restrict__ Wcb,
                                                 float* __restrict__ CBs) {
  __shared__ float xs[DIN_];
  const int row = blockIdx.x;  // b*S + s
  const int tid = threadIdx.x;
  #pragma unroll
  for (int it = 0; it < 4; ++it)
    xs[tid + it * 256] = x[(size_t)row * DIN_ + tid + it * 256];
  __syncthreads();
  const int lane = tid & 63, w = tid >> 6;
  const float SC = 0.125f * 1.44269504088896f;
  #pragma unroll
  for (int hh = 0; hh < 4; ++hh) {
    const int hidx = w * 4 + hh;
    float p = 0.f;
    for (int c = lane; c < DIN_; c += 64)
      p += xs[c] * Wcb[(size_t)hidx * DIN_ + c];
    #pragma unroll
    for (int mk = 1; mk < 64; mk <<= 1) p += __shfl_xor(p, mk);
    if (lane == 0) {
      const int bb = row / S_, ss = row % S_;
      CBs[((size_t)bb * H_ + hidx) * S_ + ss] = p * SC;
    }
  }
}

// ---------------- bf16 NT GEMM: C[M,1024] = A[M,1024] * Bw[1024,1024]^T ----------
// mode 0: outb=bf16(acc); mode 1: outb=bf16(acc+bias); mode 2: outf=acc+bias+resid
// mode 3: transposed-bf16 store: outb is Vt_g[b][col][s], value = acc+bias
__global__ __launch_bounds__(256, 2) void gemm_nt(
    const short* __restrict__ A, const short* __restrict__ Bw,
    const float* __restrict__ bias, const float* __restrict__ resid,
    short* __restrict__ outb, float* __restrict__ outf, int mode) {
  const int KD = 1024, ND = 1024;
  __shared__ short As[64][72];
  __shared__ short Bs[64][72];
  const int tid  = threadIdx.x;
  const int lane = tid & 63;
  const int w    = tid >> 6;
  const int quad = lane >> 4;
  const int l16  = lane & 15;
  const int m0   = blockIdx.y * 64;
  const int n0   = blockIdx.x * 64;
  const int wm   = (w >> 1) * 32;
  const int wn   = (w & 1) * 32;

  const float4v zero = {0.f, 0.f, 0.f, 0.f};
  float4v acc[2][2];
  acc[0][0] = zero; acc[0][1] = zero; acc[1][0] = zero; acc[1][1] = zero;

  for (int k0 = 0; k0 < KD; k0 += 64) {
    __syncthreads();
    #pragma unroll
    for (int it = 0; it < 2; ++it) {
      int idx = tid + it * 256;
      int row = idx >> 3, seg = idx & 7;
      *(short8*)&As[row][seg * 8] =
          *(const short8*)(A + (size_t)(m0 + row) * KD + k0 + seg * 8);
      *(short8*)&Bs[row][seg * 8] =
          *(const short8*)(Bw + (size_t)(n0 + row) * KD + k0 + seg * 8);
    }
    __syncthreads();
    #pragma unroll
    for (int ks = 0; ks < 2; ++ks) {
      short8 af0 = *(short8*)&As[wm + l16][ks * 32 + quad * 8];
      short8 af1 = *(short8*)&As[wm + 16 + l16][ks * 32 + quad * 8];
      short8 bg0 = *(short8*)&Bs[wn + l16][ks * 32 + quad * 8];
      short8 bg1 = *(short8*)&Bs[wn + 16 + l16][ks * 32 + quad * 8];
      acc[0][0] = __builtin_amdgcn_mfma_f32_16x16x32_bf16(af0, bg0, acc[0][0], 0, 0, 0);
      acc[0][1] = __builtin_amdgcn_mfma_f32_16x16x32_bf16(af0, bg1, acc[0][1], 0, 0, 0);
      acc[1][0] = __builtin_amdgcn_mfma_f32_16x16x32_bf16(af1, bg0, acc[1][0], 0, 0, 0);
      acc[1][1] = __builtin_amdgcn_mfma_f32_16x16x32_bf16(af1, bg1, acc[1][1], 0, 0, 0);
    }
  }

  #pragma unroll
  for (int mt = 0; mt < 2; ++mt)
    #pragma unroll
    for (int nt = 0; nt < 2; ++nt)
      #pragma unroll
      for (int r = 0; r < 4; ++r) {
        int row = m0 + wm + mt * 16 + quad * 4 + r;
        int col = n0 + wn + nt * 16 + l16;
        float v = acc[mt][nt][r];
        if (mode >= 1) v += bias[col];
        if (mode == 2)
          outf[(size_t)row * ND + col] = v + resid[(size_t)row * ND + col];
        else if (mode == 3) {
          int bb = row >> 11, ss = row & 2047;
          outb[((size_t)bb * DV_ + col) * S_ + ss] = f_to_bf16s(v);
        } else
          outb[(size_t)row * ND + col] = f_to_bf16s(v);
      }
}

// ---------------- fused collaborative attention v2 ----------------
// 32x32x16 MFMA computing S^T (rows=keys in regs, cols=queries in lanes).
// Block: 128 queries x 1 head. Wave w owns queries [i0+32w, i0+32w+32).
// Softmax is lane-local (col = lane&31) after one shfl_xor(32).
// P^T stays in registers, reshaped to PV B-frags via shfl/cndmask.
__global__ __launch_bounds__(256, 2) void attn_kernel(
    const short* __restrict__ Qb, const short* __restrict__ Kb,
    const short* __restrict__ Vtg, const float* __restrict__ mixing,
    const float* __restrict__ CBs, short* __restrict__ ctxb) {
  __shared__ short Ks[128][136];   // 128 keys x 128-k chunk (+8 pad -> 68 dw stride)
  __shared__ short Vt[64][136];    // V^T tile: [dv][j]
  __shared__ short mix_s[DK_];     // mix[h,:] * SC, bf16
  __shared__ float cb_s[128];

  const int tid = threadIdx.x;
  const int lane = tid & 63;
  const int l32 = lane & 31;
  const int l1  = lane >> 5;
  const int w   = tid >> 6;
  const int i0  = blockIdx.x * 128;
  const int h   = blockIdx.y;
  const int b   = blockIdx.z;

  const float SC = 0.125f * 1.44269504088896f;
  for (int c = tid; c < DK_; c += 256)
    mix_s[c] = f_to_bf16s(mixing[(size_t)h * DK_ + c] * SC);

  const int iq = i0 + w * 32 + l32;                       // this lane's query
  const short* qptr = Qb + ((size_t)b * S_ + iq) * DK_;
  const short* kbase = Kb + (size_t)b * S_ * DK_;
  const short* vtb   = Vtg + ((size_t)b * DV_ + h * DH_) * S_;
  const float* cbp   = CBs + ((size_t)b * H_ + h) * S_;

  float16v accS[4], accO[2];
  #pragma unroll
  for (int g = 0; g < 2; ++g)
    #pragma unroll
    for (int r = 0; r < 16; ++r) accO[g][r] = 0.f;
  float m_run = -1e30f, l_run = 0.f;

  const int krow = tid >> 1;            // K stage: 128 rows x 256B, 2 thr/row
  const int koff = (tid & 1) * 64;
  const int vrow = tid >> 2;            // Vt stage: 64 rows x 256B, 4 thr/row
  const int voff = (tid & 3) * 32;

  for (int j0 = 0; j0 < S_; j0 += 128) {
    #pragma unroll
    for (int f = 0; f < 4; ++f)
      #pragma unroll
      for (int r = 0; r < 16; ++r) accS[f][r] = 0.f;

    for (int kc = 0; kc < 8; ++kc) {
      // ---- issue global loads before the barrier ----
      short8 qraw[8];
      #pragma unroll
      for (int ks = 0; ks < 8; ++ks)
        qraw[ks] = *(const short8*)(qptr + kc * 128 + ks * 16 + l1 * 8);
      short8 kreg[8];
      #pragma unroll
      for (int it = 0; it < 8; ++it)
        kreg[it] = *(const short8*)(kbase + (size_t)(j0 + krow) * DK_ +
                                    kc * 128 + koff + it * 8);
      short8 vreg[4];
      if (kc == 0) {
        #pragma unroll
        for (int it = 0; it < 4; ++it)
          vreg[it] = *(const short8*)(vtb + (size_t)vrow * S_ + j0 + voff + it * 8);
      }
      __syncthreads();   // previous consumers of Ks (and Vt on kc==0) done
      #pragma unroll
      for (int it = 0; it < 8; ++it)
        *(short8*)&Ks[krow][koff + it * 8] = kreg[it];
      if (kc == 0) {
        #pragma unroll
        for (int it = 0; it < 4; ++it)
          *(short8*)&Vt[vrow][voff + it * 8] = vreg[it];
        if (tid < 128) cb_s[tid] = cbp[j0 + tid];
      }
      __syncthreads();

      // ---- build Qm B-frags: qm = q * mix * SC (bf16, truncated pack) ----
      short8 qm[8];
      #pragma unroll
      for (int ks = 0; ks < 8; ++ks) {
        short8 mf = *(short8*)&mix_s[kc * 128 + ks * 16 + l1 * 8];
        float p[8];
        #pragma unroll
        for (int e = 0; e < 8; ++e)
          p[e] = bf16s_to_f(qraw[ks][e]) * bf16s_to_f(mf[e]);
        union { short8 s; unsigned u[4]; } qq;
        #pragma unroll
        for (int d = 0; d < 4; ++d) qq.u[d] = pack2bf(p[2 * d + 1], p[2 * d]);
        qm[ks] = qq.s;
      }
      // ---- S^T MFMAs: A = K rows (LDS), B = qm (regs) ----
      #pragma unroll
      for (int ks = 0; ks < 8; ++ks) {
        #pragma unroll
        for (int f = 0; f < 4; ++f) {
          short8 af = *(short8*)&Ks[f * 32 + l32][ks * 16 + l1 * 8];
          accS[f] = __builtin_amdgcn_mfma_f32_32x32x16_bf16(af, qm[ks], accS[f], 0, 0, 0);
        }
      }
    }

    // ---- online softmax: lane-local over 64 in-reg values + 1 shfl ----
    float tmax = -1e30f;
    #pragma unroll
    for (int f = 0; f < 4; ++f)
      #pragma unroll
      for (int q = 0; q < 4; ++q) {
        float4 cbv = *(float4*)&cb_s[f * 32 + q * 8 + l1 * 4];
        #pragma unroll
        for (int c = 0; c < 4; ++c) {
          accS[f][4 * q + c] += ((const float*)&cbv)[c];
          tmax = fmaxf(tmax, accS[f][4 * q + c]);
        }
      }
    tmax = fmaxf(tmax, __shfl_xor(tmax, 32));
    const float mnew = fmaxf(m_run, tmax);
    const float alpha = exp2f(m_run - mnew);
    float tsum = 0.f;
    #pragma unroll
    for (int f = 0; f < 4; ++f)
      #pragma unroll
      for (int r = 0; r < 16; ++r) {
        float pv = exp2f(accS[f][r] - mnew);
        accS[f][r] = pv;
        tsum += pv;
      }
    tsum += __shfl_xor(tsum, 32);
    l_run = l_run * alpha + tsum;
    m_run = mnew;
    #pragma unroll
    for (int g = 0; g < 2; ++g)
      #pragma unroll
      for (int r = 0; r < 16; ++r) accO[g][r] *= alpha;

    // ---- PV: O^T[dv][i] += V^T[dv][j] @ P^T[j][i] ----
    #pragma unroll
    for (int cpv = 0; cpv < 8; ++cpv) {
      const int t = cpv & 1, fp = cpv >> 1;
      float xo[4], yo[4], lo[4], hi[4];
      #pragma unroll
      for (int c = 0; c < 4; ++c) {
        xo[c] = __shfl_xor(accS[fp][8 * t + c], 32);      // other half's x-group
        yo[c] = __shfl_xor(accS[fp][8 * t + 4 + c], 32);  // other half's y-group
      }
      #pragma unroll
      for (int c = 0; c < 4; ++c) {
        lo[c] = l1 ? yo[c] : accS[fp][8 * t + c];
        hi[c] = l1 ? accS[fp][8 * t + 4 + c] : xo[c];
      }
      union { short8 s; unsigned u[4]; } pb;
      pb.u[0] = pack2bf(lo[1], lo[0]);
      pb.u[1] = pack2bf(lo[3], lo[2]);
      pb.u[2] = pack2bf(hi[1], hi[0]);
      pb.u[3] = pack2bf(hi[3], hi[2]);
      #pragma unroll
      for (int g = 0; g < 2; ++g) {
        short8 vf = *(short8*)&Vt[g * 32 + l32][cpv * 16 + l1 * 8];
        accO[g] = __builtin_amdgcn_mfma_f32_32x32x16_bf16(vf, pb.s, accO[g], 0, 0, 0);
      }
    }
  }

  // ---- epilogue: normalize, store ctx (rows=dv, col=lane => scattered 8B) ----
  const float rl = 1.0f / l_run;
  short* cbase = ctxb + ((size_t)b * S_ + iq) * DV_ + h * DH_;
  #pragma unroll
  for (int g = 0; g < 2; ++g)
    #pragma unroll
    for (int q = 0; q < 4; ++q) {
      const int dv = g * 32 + 8 * q + 4 * l1;     // rows 4q..4q+3 consecutive
      union { ushort4 u4; short s[4]; } ov;
      #pragma unroll
      for (int r = 0; r < 4; ++r)
        ov.s[r] = f_to_bf16s(accO[g][4 * q + r] * rl);
      *(ushort4*)(cbase + dv) = ov.u4;
    }
}

// ---------------- LayerNorm in-place on d_out ----------------
__global__ __launch_bounds__(256) void ln_kernel(float* __restrict__ out,
                                                 const float* __restrict__ gamma,
                                                 const float* __restrict__ beta) {
  __shared__ float red[8];
  const int row = blockIdx.x;
  const int tid = threadIdx.x;
  float* p = out + (size_t)row * DOUT_;
  float4 v = ((const float4*)p)[tid];
  float s = v.x + v.y + v.z + v.w;
  #pragma unroll
  for (int mk = 1; mk < 64; mk <<= 1) s += __shfl_xor(s, mk);
  if ((tid & 63) == 0) red[tid >> 6] = s;
  __syncthreads();
  const float mean = (red[0] + red[1] + red[2] + red[3]) * (1.0f / 1024.0f);
  const float d0 = v.x - mean, d1 = v.y - mean, d2 = v.z - mean, d3 = v.w - mean;
  float sq = d0 * d0 + d1 * d1 + d2 * d2 + d3 * d3;
  #pragma unroll
  for (int mk = 1; mk < 64; mk <<= 1) sq += __shfl_xor(sq, mk);
  if ((tid & 63) == 0) red[4 + (tid >> 6)] = sq;
  __syncthreads();
  const float var = (red[4] + red[5] + red[6] + red[7]) * (1.0f / 1024.0f);
  const float rstd = rsqrtf(var + 1e-5f);
  float4 g = ((const float4*)gamma)[tid];
  float4 bt = ((const float4*)beta)[tid];
  float4 o;
  o.x = d0 * rstd * g.x + bt.x;
  o.y = d1 * rstd * g.y + bt.y;
  o.z = d2 * rstd * g.z + bt.z;
  o.w = d3 * rstd * g.w + bt.w;
  ((float4*)p)[tid] = o;
}

extern "C" void kernel_launch(void* const* d_in, const int* in_sizes, int n_in,
                              void* d_out, int out_size, void* d_ws, size_t ws_size,
                              hipStream_t stream) {
  (void)in_sizes; (void)n_in; (void)out_size; (void)ws_size;
  const float* x      = (const float*)d_in[0];
  const float* Wq     = (const float*)d_in[1];
  const float* Wk     = (const float*)d_in[2];
  const float* Wcb    = (const float*)d_in[3];
  const float* Wv     = (const float*)d_in[4];
  const float* bv     = (const float*)d_in[5];
  const float* mixing = (const float*)d_in[6];
  const float* Wd     = (const float*)d_in[7];
  const float* bd     = (const float*)d_in[8];
  const float* gamma  = (const float*)d_in[9];
  const float* beta   = (const float*)d_in[10];
  float* out = (float*)d_out;

  short* p = (short*)d_ws;
  short* xb   = p; p += (size_t)M_ * DIN_;
  short* Qb   = p; p += (size_t)M_ * DK_;
  short* Kb   = p; p += (size_t)M_ * DK_;
  short* Vtg  = p; p += (size_t)B_ * DV_ * S_;   // V^T: [b][dv][s]
  short* ctxb = p; p += (size_t)M_ * DV_;
  short* Wqb  = p; p += (size_t)DK_ * DIN_;
  short* Wkb  = p; p += (size_t)DK_ * DIN_;
  short* Wvb  = p; p += (size_t)DV_ * DIN_;
  short* Wdb  = p; p += (size_t)DOUT_ * DV_;
  float* CBs  = (float*)p;   // B*H*S floats

  cast_kernel<<<dim3(M_ * DIN_ / 1024), 256, 0, stream>>>(x, xb, M_ * DIN_ / 4);
  cast_kernel<<<dim3(DK_ * DIN_ / 1024), 256, 0, stream>>>(Wq, Wqb, DK_ * DIN_ / 4);
  cast_kernel<<<dim3(DK_ * DIN_ / 1024), 256, 0, stream>>>(Wk, Wkb, DK_ * DIN_ / 4);
  cast_kernel<<<dim3(DV_ * DIN_ / 1024), 256, 0, stream>>>(Wv, Wvb, DV_ * DIN_ / 4);
  cast_kernel<<<dim3(DOUT_ * DV_ / 1024), 256, 0, stream>>>(Wd, Wdb, DOUT_ * DV_ / 4);
  cb_kernel<<<dim3(M_), 256, 0, stream>>>(x, Wcb, CBs);

  dim3 gg(DOUT_ / 64, M_ / 64);
  gemm_nt<<<gg, 256, 0, stream>>>(xb, Wqb, nullptr, nullptr, Qb, nullptr, 0);
  gemm_nt<<<gg, 256, 0, stream>>>(xb, Wkb, nullptr, nullptr, Kb, nullptr, 0);
  gemm_nt<<<gg, 256, 0, stream>>>(xb, Wvb, bv, nullptr, Vtg, nullptr, 3);  // V^T + bias

  attn_kernel<<<dim3(S_ / 128, H_, B_), 256, 0, stream>>>(Qb, Kb, Vtg, mixing, CBs, ctxb);

  gemm_nt<<<gg, 256, 0, stream>>>(ctxb, Wdb, bd, x, nullptr, out, 2);
  ln_kernel<<<dim3(M_), 256, 0, stream>>>(out, gamma, beta);
}